// Round 1
// baseline (796.029 us; speedup 1.0000x reference)
//
#include <hip/hip_runtime.h>
#include <math.h>

// Problem constants (from reference)
constexpr int NQ = 4096, NK = 1024, CIN = 128, CKV = 256, E = 128, H = 8, D = 16, LAYERS = 3;
constexpr float SCALE = 1.0f / 256.0f;      // 1 / D^2
constexpr float CLAMP_MAX = 65503.0f;

__device__ __forceinline__ float dot4(float4 a, float4 b) {
  return a.x * b.x + a.y * b.y + a.z * b.z + a.w * b.w;
}

// ---------------- block reduction helper (256 threads, 4 waves) ----------------
__device__ __forceinline__ void block_reduce2(float& a, float& b, float* red) {
#pragma unroll
  for (int off = 32; off > 0; off >>= 1) {
    a += __shfl_down(a, off, 64);
    b += __shfl_down(b, off, 64);
  }
  int lane = threadIdx.x & 63, wid = threadIdx.x >> 6;
  if (lane == 0) { red[wid * 2] = a; red[wid * 2 + 1] = b; }
  __syncthreads();
  if (threadIdx.x == 0) {
    float sa = 0.f, sb = 0.f;
#pragma unroll
    for (int w = 0; w < 4; w++) { sa += red[w * 2]; sb += red[w * 2 + 1]; }
    red[0] = sa; red[1] = sb;
  }
  __syncthreads();
  a = red[0]; b = red[1];
}

// ---------------- GroupNorm: partial sums (2048 floats per block) ----------------
__global__ __launch_bounds__(256) void gn_partial(const float* __restrict__ in,
                                                  float* __restrict__ partials) {
  __shared__ float red[8];
  const float4* p = (const float4*)in + (size_t)blockIdx.x * 512;
  float s = 0.f, sq = 0.f;
#pragma unroll
  for (int i = 0; i < 2; i++) {
    float4 v = p[threadIdx.x + i * 256];
    s += v.x + v.y + v.z + v.w;
    sq += v.x * v.x + v.y * v.y + v.z * v.z + v.w * v.w;
  }
  block_reduce2(s, sq, red);
  if (threadIdx.x == 0) {
    partials[blockIdx.x * 2] = s;
    partials[blockIdx.x * 2 + 1] = sq;
  }
}

// ---------------- GroupNorm: finalize per-group stats ----------------
__global__ __launch_bounds__(64) void gn_finalize(const float* __restrict__ partials,
                                                  float* __restrict__ stats, int bpg,
                                                  float inv_n) {
  int g = blockIdx.x, lane = threadIdx.x;
  float s = 0.f, sq = 0.f;
  if (lane < bpg) {
    s = partials[(g * bpg + lane) * 2];
    sq = partials[(g * bpg + lane) * 2 + 1];
  }
#pragma unroll
  for (int off = 32; off > 0; off >>= 1) {
    s += __shfl_down(s, off, 64);
    sq += __shfl_down(sq, off, 64);
  }
  if (lane == 0) {
    float mu = s * inv_n;
    float var = sq * inv_n - mu * mu;
    stats[g * 2] = mu;
    stats[g * 2 + 1] = rsqrtf(var + 1e-5f);
  }
}

// ---------------- GroupNorm: apply (+optional ReLU) ----------------
__global__ __launch_bounds__(256) void gn_apply(const float* __restrict__ in,
                                                float* __restrict__ out,
                                                const float* __restrict__ stats,
                                                const float* __restrict__ w,
                                                const float* __restrict__ b,
                                                int n4, int epg4, int relu) {
  int f = blockIdx.x * 256 + threadIdx.x;
  int c = f / n4;       // flat channel index (matches flat w/b layout)
  int g = f / epg4;     // flat group index
  float mu = stats[2 * g], rs = stats[2 * g + 1];
  float sc = w[c] * rs, sh = b[c] - mu * sc;
  float4 v = ((const float4*)in)[f];
  float4 o;
  o.x = v.x * sc + sh; o.y = v.y * sc + sh; o.z = v.z * sc + sh; o.w = v.w * sc + sh;
  if (relu) {
    o.x = fmaxf(o.x, 0.f); o.y = fmaxf(o.y, 0.f);
    o.z = fmaxf(o.z, 0.f); o.w = fmaxf(o.w, 0.f);
  }
  ((float4*)out)[f] = o;
}

// ---------------- 1x1-conv projection: out[l][e][n] = sum_c W[l,e,c]*in[(l),c,n] + B[l,e] ----
__global__ __launch_bounds__(256) void proj_kernel(const float* __restrict__ in,
                                                   const float* __restrict__ W,
                                                   const float* __restrict__ B,
                                                   float* __restrict__ out,
                                                   int Cin, int N, int per_l) {
  int f = blockIdx.x * 256 + threadIdx.x;
  int n4c = N >> 2;
  int n0 = (f % n4c) * 4;
  int e0 = ((f / n4c) & 31) * 4;
  int l = f / (n4c * 32);
  const float* inl = in + (per_l ? (size_t)l * Cin * N : 0);
  const float* Wl = W + (size_t)l * E * Cin;
  float4 acc[4];
#pragma unroll
  for (int i = 0; i < 4; i++) acc[i] = make_float4(0.f, 0.f, 0.f, 0.f);
  for (int c = 0; c < Cin; c++) {
    float4 v = *(const float4*)(inl + (size_t)c * N + n0);
    float wv[4];
#pragma unroll
    for (int i = 0; i < 4; i++) wv[i] = Wl[(e0 + i) * Cin + c];
#pragma unroll
    for (int i = 0; i < 4; i++) {
      acc[i].x += wv[i] * v.x; acc[i].y += wv[i] * v.y;
      acc[i].z += wv[i] * v.z; acc[i].w += wv[i] * v.w;
    }
  }
#pragma unroll
  for (int i = 0; i < 4; i++) {
    float bv = B[l * E + e0 + i];
    acc[i].x += bv; acc[i].y += bv; acc[i].z += bv; acc[i].w += bv;
    *(float4*)(out + ((size_t)l * E + e0 + i) * N + n0) = acc[i];
  }
}

// ---------------- scores: S[h,q,k] = min(SCALE * sum_d Q[h d q] K[h d k], CLAMP) ----------------
__global__ __launch_bounds__(256) void score_kernel(const float* __restrict__ qn,
                                                    const float* __restrict__ kn,
                                                    float* __restrict__ sbuf, int l) {
  int f = blockIdx.x * 256 + threadIdx.x;
  int k0 = (f & 255) * 4;
  int q0 = ((f >> 8) & 1023) * 4;
  int h = f >> 18;
  const float* qp = qn + (size_t)l * E * NQ + (size_t)h * D * NQ;
  const float* kp = kn + (size_t)l * E * NK + (size_t)h * D * NK;
  float4 acc[4];
#pragma unroll
  for (int i = 0; i < 4; i++) acc[i] = make_float4(0.f, 0.f, 0.f, 0.f);
#pragma unroll
  for (int d = 0; d < 16; d++) {
    float4 kv = *(const float4*)(kp + d * NK + k0);
    float qv[4];
#pragma unroll
    for (int i = 0; i < 4; i++) qv[i] = qp[d * NQ + q0 + i];
#pragma unroll
    for (int i = 0; i < 4; i++) {
      acc[i].x += qv[i] * kv.x; acc[i].y += qv[i] * kv.y;
      acc[i].z += qv[i] * kv.z; acc[i].w += qv[i] * kv.w;
    }
  }
#pragma unroll
  for (int i = 0; i < 4; i++) {
    float4 o;
    o.x = fminf(acc[i].x * SCALE, CLAMP_MAX);
    o.y = fminf(acc[i].y * SCALE, CLAMP_MAX);
    o.z = fminf(acc[i].z * SCALE, CLAMP_MAX);
    o.w = fminf(acc[i].w * SCALE, CLAMP_MAX);
    *(float4*)(sbuf + ((size_t)h * NQ + q0 + i) * NK + k0) = o;
  }
}

// ---------------- softmax + PV per (h, 16-query tile) ----------------
__global__ __launch_bounds__(256) void softmax_pv_kernel(const float* __restrict__ vn,
                                                         float* __restrict__ sbuf,
                                                         float* __restrict__ ob,
                                                         int l, int write_w) {
  constexpr int STR = 140;                 // padded row stride (floats), 16B-aligned
  __shared__ float rowm[16];
  __shared__ float rowri[16];
  __shared__ float buf[2 * 16 * STR];      // Wl + Vl; reused as red[16][256] at the end

  int h = blockIdx.y;
  int q0 = blockIdx.x * 16;
  int t = threadIdx.x;
  int lane = t & 63;
  int wid = t >> 6;

  float* Sbase = sbuf + ((size_t)h * NQ + q0) * NK;
  const float* Vbase = vn + (size_t)l * E * NK + (size_t)h * D * NK;

  // Phase A: per-row max and exp-sum (wave per 4 rows)
  for (int i = 0; i < 4; i++) {
    int r = wid * 4 + i;
    const float4* row = (const float4*)(Sbase + (size_t)r * NK);
    float4 v0 = row[lane];
    float4 v1 = row[lane + 64];
    float4 v2 = row[lane + 128];
    float4 v3 = row[lane + 192];
    float m = fmaxf(fmaxf(fmaxf(v0.x, v0.y), fmaxf(v0.z, v0.w)),
                    fmaxf(fmaxf(v1.x, v1.y), fmaxf(v1.z, v1.w)));
    m = fmaxf(m, fmaxf(fmaxf(fmaxf(v2.x, v2.y), fmaxf(v2.z, v2.w)),
                       fmaxf(fmaxf(v3.x, v3.y), fmaxf(v3.z, v3.w))));
#pragma unroll
    for (int off = 32; off > 0; off >>= 1) m = fmaxf(m, __shfl_xor(m, off, 64));
    float s = __expf(v0.x - m) + __expf(v0.y - m) + __expf(v0.z - m) + __expf(v0.w - m)
            + __expf(v1.x - m) + __expf(v1.y - m) + __expf(v1.z - m) + __expf(v1.w - m)
            + __expf(v2.x - m) + __expf(v2.y - m) + __expf(v2.z - m) + __expf(v2.w - m)
            + __expf(v3.x - m) + __expf(v3.y - m) + __expf(v3.z - m) + __expf(v3.w - m);
#pragma unroll
    for (int off = 32; off > 0; off >>= 1) s += __shfl_xor(s, off, 64);
    if (lane == 0) { rowm[r] = m; rowri[r] = 1.f / s; }
  }
  __syncthreads();

  float acc[16];
#pragma unroll
  for (int i = 0; i < 16; i++) acc[i] = 0.f;
  int sl = t & 15;          // k-slice
  int pair = t >> 4;        // which (4q,4d) tile
  int qb = (pair & 3) * 4;
  int db = (pair >> 2) * 4;
  float* Wl = buf;
  float* Vl = buf + 16 * STR;

  for (int c = 0; c < 8; c++) {
    int kb = c * 128;
    __syncthreads();
#pragma unroll
    for (int i = 0; i < 8; i++) {
      int idx = i * 256 + t;
      int r = idx >> 7;
      int kk = idx & 127;
      float sv = Sbase[(size_t)r * NK + kb + kk];
      float wv = __expf(sv - rowm[r]) * rowri[r];
      Wl[r * STR + kk] = wv;
      if (write_w) Sbase[(size_t)r * NK + kb + kk] = wv;   // final w_att (layer 2)
      Vl[r * STR + kk] = Vbase[(size_t)r * NK + kb + kk];
    }
    __syncthreads();
#pragma unroll
    for (int j = 0; j < 2; j++) {
      int kk = sl * 4 + j * 64;
      float4 wv0 = *(const float4*)(Wl + (qb + 0) * STR + kk);
      float4 wv1 = *(const float4*)(Wl + (qb + 1) * STR + kk);
      float4 wv2 = *(const float4*)(Wl + (qb + 2) * STR + kk);
      float4 wv3 = *(const float4*)(Wl + (qb + 3) * STR + kk);
      float4 vv0 = *(const float4*)(Vl + (db + 0) * STR + kk);
      float4 vv1 = *(const float4*)(Vl + (db + 1) * STR + kk);
      float4 vv2 = *(const float4*)(Vl + (db + 2) * STR + kk);
      float4 vv3 = *(const float4*)(Vl + (db + 3) * STR + kk);
      acc[0]  += dot4(wv0, vv0); acc[1]  += dot4(wv0, vv1);
      acc[2]  += dot4(wv0, vv2); acc[3]  += dot4(wv0, vv3);
      acc[4]  += dot4(wv1, vv0); acc[5]  += dot4(wv1, vv1);
      acc[6]  += dot4(wv1, vv2); acc[7]  += dot4(wv1, vv3);
      acc[8]  += dot4(wv2, vv0); acc[9]  += dot4(wv2, vv1);
      acc[10] += dot4(wv2, vv2); acc[11] += dot4(wv2, vv3);
      acc[12] += dot4(wv3, vv0); acc[13] += dot4(wv3, vv1);
      acc[14] += dot4(wv3, vv2); acc[15] += dot4(wv3, vv3);
    }
  }
  __syncthreads();
  // reduce the 16 k-slices
  float* red = buf;   // [16 slices][256 outputs]
#pragma unroll
  for (int i = 0; i < 16; i++) red[sl * 256 + pair * 16 + i] = acc[i];
  __syncthreads();
  int q = t & 15, d = t >> 4;
  int pr = (q >> 2) | ((d >> 2) << 2);
  int e = (q & 3) * 4 + (d & 3);
  float o = 0.f;
#pragma unroll
  for (int s2 = 0; s2 < 16; s2++) o += red[s2 * 256 + pr * 16 + e];
  ob[((size_t)l * E + h * D + d) * NQ + q0 + q] = o;
}

// ---------------- combine: out[c,n] = x + xq + (1/3) sum_l (cb + sum_e cw[l,c,e]*o[l,e,n]) ----
__global__ __launch_bounds__(256) void combine_kernel(const float* __restrict__ x,
                                                      const float* __restrict__ xq,
                                                      const float* __restrict__ ob,
                                                      const float* __restrict__ cw,
                                                      const float* __restrict__ cb,
                                                      float* __restrict__ out) {
  int f = blockIdx.x * 256 + threadIdx.x;
  int n0 = (f & 1023) * 4;
  int c0 = (f >> 10) * 4;
  float4 acc[4];
#pragma unroll
  for (int i = 0; i < 4; i++) acc[i] = make_float4(0.f, 0.f, 0.f, 0.f);
  for (int l = 0; l < LAYERS; l++) {
    const float* obl = ob + (size_t)l * E * NQ;
    const float* cwl = cw + (size_t)l * CIN * E;
#pragma unroll 4
    for (int e = 0; e < E; e++) {
      float4 ov = *(const float4*)(obl + (size_t)e * NQ + n0);
      float wv[4];
#pragma unroll
      for (int i = 0; i < 4; i++) wv[i] = cwl[(c0 + i) * E + e];
#pragma unroll
      for (int i = 0; i < 4; i++) {
        acc[i].x += wv[i] * ov.x; acc[i].y += wv[i] * ov.y;
        acc[i].z += wv[i] * ov.z; acc[i].w += wv[i] * ov.w;
      }
    }
  }
  const float third = 1.f / 3.f;
#pragma unroll
  for (int i = 0; i < 4; i++) {
    int c = c0 + i;
    float bsum = (cb[c] + cb[CIN + c] + cb[2 * CIN + c]) * third;
    float4 xv = *(const float4*)(x + (size_t)c * NQ + n0);
    float4 xqv = *(const float4*)(xq + (size_t)c * NQ + n0);
    float4 o;
    o.x = xv.x + xqv.x + acc[i].x * third + bsum;
    o.y = xv.y + xqv.y + acc[i].y * third + bsum;
    o.z = xv.z + xqv.z + acc[i].z * third + bsum;
    o.w = xv.w + xqv.w + acc[i].w * third + bsum;
    *(float4*)(out + (size_t)c * NQ + n0) = o;
  }
}

extern "C" void kernel_launch(void* const* d_in, const int* in_sizes, int n_in,
                              void* d_out, int out_size, void* d_ws, size_t ws_size,
                              hipStream_t stream) {
  (void)in_sizes; (void)n_in; (void)out_size;
  const float* x    = (const float*)d_in[0];
  const float* xgi  = (const float*)d_in[1];
  // d_in[2], d_in[3] (xyz, xyz_global) unused by the reference
  const float* gn1w = (const float*)d_in[4];
  const float* gn1b = (const float*)d_in[5];
  const float* gn2w = (const float*)d_in[6];
  const float* gn2b = (const float*)d_in[7];
  const float* qw   = (const float*)d_in[8];
  const float* qb   = (const float*)d_in[9];
  const float* kw   = (const float*)d_in[10];
  const float* kb   = (const float*)d_in[11];
  const float* vw   = (const float*)d_in[12];
  const float* vb   = (const float*)d_in[13];
  const float* qgnw = (const float*)d_in[14];
  const float* qgnb = (const float*)d_in[15];
  const float* cw   = (const float*)d_in[16];
  const float* cb   = (const float*)d_in[17];

  float* ws = (float*)d_ws;
  float* xq    = ws;                 // 524288   [c][n]
  float* xgb   = ws + 524288;        // 786432   [l][c][n]
  float* qn    = ws + 1310720;       // 1572864  [l][e][n]
  float* kn    = ws + 2883584;       // 393216   [l][e][k]
  float* vn    = ws + 3276800;       // 393216   [l][e][k]
  float* ob    = ws + 3670016;       // 1572864  [l][e][n]
  float* part  = ws + 5242880;       // 1536
  float* stats = ws + 5244928;       // 96
  if (ws_size < (size_t)5245056 * sizeof(float)) return;  // need ~21 MB scratch

  float* outp = (float*)d_out;            // 524288 floats: final out
  float* sbuf = outp + 524288;            // 33554432 floats: w_att / per-layer score scratch

  // GroupNorm(8) + ReLU on x -> xq
  gn_partial<<<256, 256, 0, stream>>>(x, part);
  gn_finalize<<<8, 64, 0, stream>>>(part, stats, 32, 1.f / 65536.f);
  gn_apply<<<512, 256, 0, stream>>>(x, xq, stats, gn1w, gn1b, 1024, 16384, 1);

  // GroupNorm(16) + ReLU on x_global -> xgb
  gn_partial<<<384, 256, 0, stream>>>(xgi, part);
  gn_finalize<<<48, 64, 0, stream>>>(part, stats, 8, 1.f / 16384.f);
  gn_apply<<<768, 256, 0, stream>>>(xgi, xgb, stats, gn2w, gn2b, 256, 4096, 1);

  // projections
  proj_kernel<<<384, 256, 0, stream>>>(xq, qw, qb, qn, 128, 4096, 0);
  proj_kernel<<<96, 256, 0, stream>>>(xgb, kw, kb, kn, 256, 1024, 1);
  proj_kernel<<<96, 256, 0, stream>>>(xgb, vw, vb, vn, 256, 1024, 1);

  // shared GroupNorm(8, qgn) on q, k, v (in place)
  gn_partial<<<768, 256, 0, stream>>>(qn, part);
  gn_finalize<<<24, 64, 0, stream>>>(part, stats, 32, 1.f / 65536.f);
  gn_apply<<<1536, 256, 0, stream>>>(qn, qn, stats, qgnw, qgnb, 1024, 16384, 0);

  gn_partial<<<192, 256, 0, stream>>>(kn, part);
  gn_finalize<<<24, 64, 0, stream>>>(part, stats, 8, 1.f / 16384.f);
  gn_apply<<<384, 256, 0, stream>>>(kn, kn, stats, qgnw, qgnb, 256, 4096, 0);

  gn_partial<<<192, 256, 0, stream>>>(vn, part);
  gn_finalize<<<24, 64, 0, stream>>>(part, stats, 8, 1.f / 16384.f);
  gn_apply<<<384, 256, 0, stream>>>(vn, vn, stats, qgnw, qgnb, 256, 4096, 0);

  // attention per layer; layer 2's normalized weights stay in sbuf (= w_att output)
  for (int l = 0; l < LAYERS; l++) {
    score_kernel<<<8192, 256, 0, stream>>>(qn, kn, sbuf, l);
    softmax_pv_kernel<<<dim3(256, 8), 256, 0, stream>>>(vn, sbuf, ob, l, l == 2 ? 1 : 0);
  }

  combine_kernel<<<128, 256, 0, stream>>>(x, xq, ob, cw, cb, outp);
}